// Round 3
// baseline (736.134 us; speedup 1.0000x reference)
//
#include <hip/hip_runtime.h>
#include <hip/hip_bf16.h>

#define B_DIM 256
#define T_DIM 512
#define K_DIM 128

// One block (128 threads = 2 waves) per (pass, batch-row).
// Thread k owns column k: E[j][k] = exp(trans[j][k]) in 128 VGPRs.
// Zero-lag normalizer, computed redundantly per thread (no broadcast needed):
//   s_k = sum_j q_{t-1}[j] * E[j][k]       (in-register matvec)
//   R   = sum_j q_{t-1}[j]                 (same LDS reads, 4 extra accumulators)
//   q_t[k] = s_k * exp(e_t[k]) / R ;  m += log R
// => q_t[k] = exp(alpha_t[k] - LSE(alpha_{t-1})), |log q| <= ~9: stable forever.
// Single barrier per step; double-buffered q in LDS.
__global__ __launch_bounds__(128, 1) void crf_pass_kernel(
    const float* __restrict__ tw,      // [B,T,K]
    const float* __restrict__ trans,   // [K,K]
    const int*   __restrict__ gold,    // [B,T]
    const int*   __restrict__ lengths, // [B]
    float*       __restrict__ wsv)     // [2*B]
{
    const int bid = blockIdx.x;
    const int b = bid & (B_DIM - 1);
    const bool clamp = bid >= B_DIM;
    const int k = threadIdx.x;         // 0..127

    __shared__ __align__(16) float qbuf[2][K_DIM];
    __shared__ float red[2];

    // column of exp(trans) into registers (statically indexed after unroll)
    float E[K_DIM];
#pragma unroll
    for (int j = 0; j < K_DIM; ++j)
        E[j] = __expf(trans[j * K_DIM + k]);

    const int len = lengths[b];
    const float* twb = tw + (size_t)b * T_DIM * K_DIM;
    const int* gb = gold + b * T_DIM;

    float m = 0.0f;
    float lastq;
    {
        float e0 = twb[k];
        int g = clamp ? gb[0] : -1;
        float q = __expf(e0);
        if (g >= 0 && g != k) q = 0.0f;
        qbuf[0][k] = q;
        lastq = q;
    }
    __syncthreads();

    // prefetch raw emissions/gold for steps 1..4
    float ec[4]; int gc[4];
#pragma unroll
    for (int i = 0; i < 4; ++i) {
        int t = 1 + i; if (t > T_DIM - 1) t = T_DIM - 1;
        ec[i] = twb[t * K_DIM + k];
        gc[i] = clamp ? gb[t] : -1;
    }

    for (int t0 = 1; t0 < len; t0 += 4) {
        // issue next chunk's loads (consumed next iteration -> latency hidden)
        float en[4]; int gn[4];
#pragma unroll
        for (int i = 0; i < 4; ++i) {
            int t = t0 + 4 + i; if (t > T_DIM - 1) t = T_DIM - 1;
            en[i] = twb[t * K_DIM + k];
            gn[i] = clamp ? gb[t] : -1;
        }

#pragma unroll
        for (int i = 0; i < 4; ++i) {
            const int t = t0 + i;
            if (t < len) {             // block-uniform
                const float4* qv = (const float4*)qbuf[(t - 1) & 1];
                float x = __expf(ec[i]);              // off critical path
                float a0 = 0.f, a1 = 0.f, a2 = 0.f, a3 = 0.f;
                float r0 = 0.f, r1 = 0.f, r2 = 0.f, r3 = 0.f;
#pragma unroll
                for (int q4 = 0; q4 < 32; ++q4) {
                    float4 pj = qv[q4];
                    a0 = fmaf(pj.x, E[4 * q4 + 0], a0);
                    a1 = fmaf(pj.y, E[4 * q4 + 1], a1);
                    a2 = fmaf(pj.z, E[4 * q4 + 2], a2);
                    a3 = fmaf(pj.w, E[4 * q4 + 3], a3);
                    r0 += pj.x; r1 += pj.y; r2 += pj.z; r3 += pj.w;
                }
                float s = (a0 + a1) + (a2 + a3);
                float R = (r0 + r1) + (r2 + r3);      // same for all threads
                float qn = s * x * __builtin_amdgcn_rcpf(R);
                int g = gc[i];
                if (g >= 0 && g != k) qn = 0.0f;
                qbuf[t & 1][k] = qn;
                lastq = qn;
                m += __logf(R);                       // uniform side chain
            }
            __syncthreads();           // single barrier per step
        }
#pragma unroll
        for (int i = 0; i < 4; ++i) { ec[i] = en[i]; gc[i] = gn[i]; }
    }

    // logZ = m + log(sum_k lastq)
    float v = lastq;
#pragma unroll
    for (int off = 32; off; off >>= 1) v += __shfl_xor(v, off);
    if ((k & 63) == 0) red[k >> 6] = v;
    __syncthreads();
    if (k == 0) wsv[bid] = m + __logf(red[0] + red[1]);
}

__global__ void crf_finalize(const float* __restrict__ wsv, float* __restrict__ out)
{
    const int tid = threadIdx.x;   // 256 threads, one per batch row
    float d = wsv[tid] - wsv[B_DIM + tid];
#pragma unroll
    for (int off = 32; off; off >>= 1) d += __shfl_xor(d, off);
    __shared__ float red[4];
    if ((tid & 63) == 0) red[tid >> 6] = d;
    __syncthreads();
    if (tid == 0) out[0] = (red[0] + red[1] + red[2] + red[3]) * (1.0f / (float)B_DIM);
}

extern "C" void kernel_launch(void* const* d_in, const int* in_sizes, int n_in,
                              void* d_out, int out_size, void* d_ws, size_t ws_size,
                              hipStream_t stream)
{
    const float* tw      = (const float*)d_in[0];
    const float* trans   = (const float*)d_in[1];
    const int*   gold    = (const int*)d_in[2];
    const int*   lengths = (const int*)d_in[3];
    float* wsv = (float*)d_ws;          // 2*B floats
    float* out = (float*)d_out;

    crf_pass_kernel<<<2 * B_DIM, 128, 0, stream>>>(tw, trans, gold, lengths, wsv);
    crf_finalize<<<1, B_DIM, 0, stream>>>(wsv, out);
}

// Round 4
// 374.532 us; speedup vs baseline: 1.9655x; 1.9655x over previous
//
#include <hip/hip_runtime.h>
#include <hip/hip_bf16.h>

#define B_DIM 256
#define T_DIM 512
#define K_DIM 128

// One block (256 threads = 4 waves) per (pass, batch-row).
// Thread t: k = t>>1 (output tag), h = t&1 (j-half). Thread holds
// E[j][k] = exp(trans[j][k]) for j in [64h, 64h+64) as 16 NAMED float4s
// (not an array -> cannot be demoted to scratch).
// Per step (single barrier):
//   s_half = sum_{j in half} q[j]*E[j][k]   (16 float4 broadcast LDS reads)
//   s      = s_half + shfl_xor(s_half, 1)   (combine halves, in-wave)
//   q'[k]  = s * exp(e_t[k]) / R ;  m += log R
//   R for NEXT step: parity shfl-reduce of q'[k] per wave -> rsum LDS.
// q'[k] = exp(alpha_t[k] - LSE(alpha_{t-1})) -> |log q| <= ~10, stable in fp32.
__global__ __launch_bounds__(256, 2) void crf_pass_kernel(
    const float* __restrict__ tw,      // [B,T,K]
    const float* __restrict__ trans,   // [K,K]
    const int*   __restrict__ gold,    // [B,T]
    const int*   __restrict__ lengths, // [B]
    float*       __restrict__ wsv)     // [2*B]
{
    const int bid = blockIdx.x;
    const int b = bid & (B_DIM - 1);
    const bool clamp = bid >= B_DIM;
    const int tid = threadIdx.x;
    const int k = tid >> 1;            // 0..127
    const int h = tid & 1;             // j-half
    const int j0 = h * 64;

    __shared__ __align__(16) float qbuf[2][K_DIM];
    __shared__ float rsum[2][4];

    // ---- E fragment: 16 named float4 registers ----
    float4 E0, E1, E2, E3, E4, E5, E6, E7, E8, E9, E10, E11, E12, E13, E14, E15;
#define LOADE(n) E##n = make_float4( \
        __expf(trans[(j0 + 4*n + 0) * K_DIM + k]), \
        __expf(trans[(j0 + 4*n + 1) * K_DIM + k]), \
        __expf(trans[(j0 + 4*n + 2) * K_DIM + k]), \
        __expf(trans[(j0 + 4*n + 3) * K_DIM + k]))
    LOADE(0); LOADE(1); LOADE(2); LOADE(3);
    LOADE(4); LOADE(5); LOADE(6); LOADE(7);
    LOADE(8); LOADE(9); LOADE(10); LOADE(11);
    LOADE(12); LOADE(13); LOADE(14); LOADE(15);
#undef LOADE

    const int len = lengths[b];
    const float* twb = tw + (size_t)b * T_DIM * K_DIM;
    const int* gb = gold + b * T_DIM;

    float m = 0.0f;
    // ---- t = 0 init ----
    {
        float e0 = twb[k];
        int g = clamp ? gb[0] : -1;
        float q = __expf(e0);
        if (g >= 0 && g != k) q = 0.0f;
        if (h == 0) qbuf[0][k] = q;
        float v = q;
#pragma unroll
        for (int off = 2; off <= 32; off <<= 1) v += __shfl_xor(v, off);
        if ((tid & 63) == 0) rsum[0][tid >> 6] = v;
    }
    __syncthreads();

    // prefetch emissions/gold for steps 1..4
    float ec[4]; int gc[4];
#pragma unroll
    for (int i = 0; i < 4; ++i) {
        int t = 1 + i; if (t > T_DIM - 1) t = T_DIM - 1;
        ec[i] = twb[t * K_DIM + k];
        gc[i] = clamp ? gb[t] : -1;
    }

    for (int t0 = 1; t0 < len; t0 += 4) {
        float en[4]; int gn[4];
#pragma unroll
        for (int i = 0; i < 4; ++i) {
            int t = t0 + 4 + i; if (t > T_DIM - 1) t = T_DIM - 1;
            en[i] = twb[t * K_DIM + k];
            gn[i] = clamp ? gb[t] : -1;
        }

#pragma unroll
        for (int i = 0; i < 4; ++i) {
            const int t = t0 + i;
            if (t < len) {             // block-uniform
                const int cur = (t - 1) & 1, nxt = t & 1;
                const float4* qv = (const float4*)&qbuf[cur][j0];
                float R = (rsum[cur][0] + rsum[cur][1]) + (rsum[cur][2] + rsum[cur][3]);
                float x = __expf(ec[i]);              // off critical path
                float a0 = 0.f, a1 = 0.f, a2 = 0.f, a3 = 0.f;
#define FMA4(n) { float4 pj = qv[n]; \
                  a0 = fmaf(pj.x, E##n.x, a0); a1 = fmaf(pj.y, E##n.y, a1); \
                  a2 = fmaf(pj.z, E##n.z, a2); a3 = fmaf(pj.w, E##n.w, a3); }
                FMA4(0);  FMA4(1);  FMA4(2);  FMA4(3);
                FMA4(4);  FMA4(5);  FMA4(6);  FMA4(7);
                FMA4(8);  FMA4(9);  FMA4(10); FMA4(11);
                FMA4(12); FMA4(13); FMA4(14); FMA4(15);
#undef FMA4
                float s_half = (a0 + a1) + (a2 + a3);
                float s = s_half + __shfl_xor(s_half, 1);   // combine j-halves
                float qn = s * x * __builtin_amdgcn_rcpf(R);
                int g = gc[i];
                if (g >= 0 && g != k) qn = 0.0f;
                m += __logf(R);
                if (h == 0) qbuf[nxt][k] = qn;
                float v = qn;                               // R for next step
#pragma unroll
                for (int off = 2; off <= 32; off <<= 1) v += __shfl_xor(v, off);
                if ((tid & 63) == 0) rsum[nxt][tid >> 6] = v;
            }
            __syncthreads();           // single barrier per step
        }
#pragma unroll
        for (int i = 0; i < 4; ++i) { ec[i] = en[i]; gc[i] = gn[i]; }
    }

    if (tid == 0) {
        const int cur = (len - 1) & 1;
        float R = (rsum[cur][0] + rsum[cur][1]) + (rsum[cur][2] + rsum[cur][3]);
        wsv[bid] = m + __logf(R);
    }
}

__global__ void crf_finalize(const float* __restrict__ wsv, float* __restrict__ out)
{
    const int tid = threadIdx.x;   // 256 threads, one per batch row
    float d = wsv[tid] - wsv[B_DIM + tid];
#pragma unroll
    for (int off = 32; off; off >>= 1) d += __shfl_xor(d, off);
    __shared__ float red[4];
    if ((tid & 63) == 0) red[tid >> 6] = d;
    __syncthreads();
    if (tid == 0) out[0] = (red[0] + red[1] + red[2] + red[3]) * (1.0f / (float)B_DIM);
}

extern "C" void kernel_launch(void* const* d_in, const int* in_sizes, int n_in,
                              void* d_out, int out_size, void* d_ws, size_t ws_size,
                              hipStream_t stream)
{
    const float* tw      = (const float*)d_in[0];
    const float* trans   = (const float*)d_in[1];
    const int*   gold    = (const int*)d_in[2];
    const int*   lengths = (const int*)d_in[3];
    float* wsv = (float*)d_ws;          // 2*B floats
    float* out = (float*)d_out;

    crf_pass_kernel<<<2 * B_DIM, 256, 0, stream>>>(tw, trans, gold, lengths, wsv);
    crf_finalize<<<1, B_DIM, 0, stream>>>(wsv, out);
}